// Round 17
// baseline (1023.212 us; speedup 1.0000x reference)
//
#include <hip/hip_runtime.h>
#include <math.h>

// Problem constants (B=2, S=4096, D=512, MAXC=32, BIAS_LEN=128, TEMP=1)
#define BB   2
#define SS   4096
#define DD   512
#define DH   256      // D/2
#define KTOP 32
#define KSEL 64       // candidate slots (one per lane)
#define TGT  48       // threshold target: count(key >= T) >= TGT (margin 16 ranks)
#define HALF 2048     // j processed in two halves to bound workspace
#define SCALE 0.044194173824159216f   // 1/sqrt(512)

typedef __bf16 bf16_t;
typedef bf16_t bf16x8 __attribute__((ext_vector_type(8)));
typedef float  f32x4  __attribute__((ext_vector_type(4)));

// decode row of triangular tile list: q in [0, r_max*(r_max+1)/2)
__device__ __forceinline__ int tri_row(int q) {
    int r = (int)((sqrtf(8.0f * q + 1.0f) - 1.0f) * 0.5f);
    while ((r + 1) * (r + 2) / 2 <= q) ++r;
    while (r * (r + 1) / 2 > q) --r;
    return r;
}

// tile-id decode shared by both scores kernels (verified R0..R16)
__device__ __forceinline__ void decode_tile(int id, int h, int& rt, int& jtl, int& jtg) {
    if (h == 0) {
        if (id < 256) { rt = 16 + (id >> 4); jtl = id & 15; }
        else { int q = id - 256; rt = tri_row(q); jtl = q - rt * (rt + 1) / 2; }
        jtg = jtl;
    } else {
        int r = tri_row(id); rt = 16 + r;
        jtl = id - r * (r + 1) / 2; jtg = jtl + 16;
    }
}

// ---------------------------------------------------------------------------
// MLP GEMM v10 (R14 VERBATIM -- measured win, 478->452): 128x128, BK=64.
// Per-(m,n) chain BITWISE fixed (ascending-k fmaf, acc+bias, exact GELU).
// Optional bf16 shadow (R11-verified fusion).
// ---------------------------------------------------------------------------
template<bool GELU>
__global__ __launch_bounds__(256)
void gemm128(const float* __restrict__ A0, const float* __restrict__ A1,
             const float* __restrict__ W0, const float* __restrict__ W1,
             const float* __restrict__ b0, const float* __restrict__ b1,
             float* __restrict__ C0, float* __restrict__ C1,
             bf16_t* __restrict__ Bs0, bf16_t* __restrict__ Bs1,
             int N, int K)
{
    __shared__ float As[64][132];   // [k][m]  (BK=64)
    __shared__ float Ws[64][132];   // [k][n]
    const int t = threadIdx.x;
    const int z = blockIdx.z;
    const float* A    = z ? A1 : A0;
    const float* W    = z ? W1 : W0;
    const float* bias = z ? b1 : b0;
    float*       C    = z ? C1 : C0;
    bf16_t*      Bsh  = z ? Bs1 : Bs0;
    const int n0 = blockIdx.x * 128;
    const int m0 = blockIdx.y * 128;

    const int kq = t & 7;          // A stager: k-quad pair (4*kq and 4*kq+32)
    const int rr = t >> 3;         // A stager: row 0..31 (+u*32)
    const int wkr = t >> 3;        // W stager: k-row 0..31 (+v*32)
    const int wnc = (t & 7) * 16;  // W stager: col group (16 cols = 4 float4)
    const float* Ab = A + (size_t)m0 * K;
    const float* Wb = W + (size_t)0 * N + n0;

    const int lane = t & 63, wav = t >> 6;
    const int wr = wav >> 1, wc = wav & 1;     // wave 2x2 over 64x64 regions
    const int li = lane >> 3, lj = lane & 7;   // 8x8 lane grid

    float acc[8][8] = {};
    float4 aR[4][2], wR[2][4];
    #pragma unroll
    for (int u = 0; u < 4; ++u) {              // prologue: chunk 0 -> regs
        int r = u * 32 + rr;
        aR[u][0] = *(const float4*)&Ab[(size_t)r * K + 4 * kq];
        aR[u][1] = *(const float4*)&Ab[(size_t)r * K + 4 * kq + 32];
    }
    #pragma unroll
    for (int v = 0; v < 2; ++v) {
        int krow = v * 32 + wkr;
        #pragma unroll
        for (int u = 0; u < 4; ++u)
            wR[v][u] = *(const float4*)&Wb[(size_t)krow * N + wnc + 4 * u];
    }

    const int nch = K >> 6;                    // BK=64 chunks
    for (int c = 0; c < nch; ++c) {
        __syncthreads();
        #pragma unroll
        for (int u = 0; u < 4; ++u) {          // A regs -> LDS (both k-quads)
            int r = u * 32 + rr;
            As[4*kq+0][r]  = aR[u][0].x; As[4*kq+1][r]  = aR[u][0].y;
            As[4*kq+2][r]  = aR[u][0].z; As[4*kq+3][r]  = aR[u][0].w;
            As[4*kq+32][r] = aR[u][1].x; As[4*kq+33][r] = aR[u][1].y;
            As[4*kq+34][r] = aR[u][1].z; As[4*kq+35][r] = aR[u][1].w;
        }
        #pragma unroll
        for (int v = 0; v < 2; ++v) {          // W regs -> LDS
            int krow = v * 32 + wkr;
            #pragma unroll
            for (int u = 0; u < 4; ++u)
                *(float4*)&Ws[krow][wnc + 4 * u] = wR[v][u];
        }
        __syncthreads();
        if (c + 1 < nch) {                     // prefetch next chunk
            int k0 = (c + 1) * 64;
            #pragma unroll
            for (int u = 0; u < 4; ++u) {
                int r = u * 32 + rr;
                aR[u][0] = *(const float4*)&Ab[(size_t)r * K + k0 + 4 * kq];
                aR[u][1] = *(const float4*)&Ab[(size_t)r * K + k0 + 4 * kq + 32];
            }
            #pragma unroll
            for (int v = 0; v < 2; ++v) {
                int krow = k0 + v * 32 + wkr;
                #pragma unroll
                for (int u = 0; u < 4; ++u)
                    wR[v][u] = *(const float4*)&Wb[(size_t)krow * N + wnc + 4 * u];
            }
        }
        #pragma unroll
        for (int kk = 0; kk < 64; ++kk) {      // conflict-free: 8 addrs x 8-bcast
            float4 a0 = *(const float4*)&As[kk][wr * 64 + li * 8];
            float4 a1 = *(const float4*)&As[kk][wr * 64 + li * 8 + 4];
            float4 b0v = *(const float4*)&Ws[kk][wc * 64 + lj * 8];
            float4 b1v = *(const float4*)&Ws[kk][wc * 64 + lj * 8 + 4];
            float av[8] = {a0.x,a0.y,a0.z,a0.w,a1.x,a1.y,a1.z,a1.w};
            float bv[8] = {b0v.x,b0v.y,b0v.z,b0v.w,b1v.x,b1v.y,b1v.z,b1v.w};
            #pragma unroll
            for (int ri = 0; ri < 8; ++ri)
                #pragma unroll
                for (int rj = 0; rj < 8; ++rj)
                    acc[ri][rj] = fmaf(av[ri], bv[rj], acc[ri][rj]);
        }
    }

    const int nb = n0 + wc * 64 + lj * 8;
    float bv0[8];
    *(float4*)&bv0[0] = *(const float4*)&bias[nb];
    *(float4*)&bv0[4] = *(const float4*)&bias[nb + 4];
    #pragma unroll
    for (int ri = 0; ri < 8; ++ri) {
        int m = m0 + wr * 64 + li * 8 + ri;
        float o[8];
        #pragma unroll
        for (int rj = 0; rj < 8; ++rj) {
            float v = acc[ri][rj] + bv0[rj];   // same op order as R3: acc + bias
            if (GELU) v = 0.5f * v * (1.0f + erff(v * 0.7071067811865475f));
            o[rj] = v;
        }
        *(float4*)&C[(size_t)m * N + nb]     = make_float4(o[0],o[1],o[2],o[3]);
        *(float4*)&C[(size_t)m * N + nb + 4] = make_float4(o[4],o[5],o[6],o[7]);
        if (Bsh) {                              // fused bf16 shadow (R11)
            bf16x8 hv;
            #pragma unroll
            for (int rj = 0; rj < 8; ++rj) hv[rj] = (bf16_t)o[rj];
            *(bf16x8*)&Bsh[(size_t)m * N + nb] = hv;
        }
    }
}

// ---------------------------------------------------------------------------
// APPROX scores (verified R7..R16): bf16 inputs + global_load_lds(16B),
// m97 schedule (double-buffered [128][32] linear LDS, 1 barrier/chunk).
// fp32 Sc (bf16 Sc unsafe: radix tie-group truncation, R10).
// ---------------------------------------------------------------------------
__device__ __forceinline__ void stage_tile(const bf16_t* __restrict__ g,
                                           bf16_t* lds, int t, int k0)
{
    const int r0 = t >> 2;          // global row 0..63 (+64 for inst 1)
    const int cb = (t & 3) * 8;     // element offset within 32-elem slice
    const int wb = (t >> 6) * 512;  // wave-uniform LDS element base
    #pragma unroll
    for (int inst = 0; inst < 2; ++inst) {
        const bf16_t* gp = g + (size_t)(inst * 64 + r0) * DD + (k0 + cb);
        bf16_t* lp = lds + inst * 2048 + wb;   // + lane*8 elems added by HW
        __builtin_amdgcn_global_load_lds(
            (const __attribute__((address_space(1))) void*)gp,
            (__attribute__((address_space(3))) void*)lp, 16, 0, 0);
    }
}

__global__ __launch_bounds__(256, 2)
void scores_approx_g(const bf16_t* __restrict__ Ib, const bf16_t* __restrict__ Fb,
                     const float* __restrict__ lb, float* __restrict__ Sc, int h)
{
    __shared__ bf16_t As[2][128 * 32];
    __shared__ bf16_t Bs[2][128 * 32];
    const int t = threadIdx.x;

    int rt, jtl, jtg;
    decode_tile(blockIdx.x, h, rt, jtl, jtg);
    const int b  = blockIdx.z;
    const int i0 = rt << 7, j0 = jtg << 7;
    const size_t bo = (size_t)b * SS * DD;
    const bf16_t* Ag = Ib + bo + (size_t)i0 * DD;
    const bf16_t* Bg = Fb + bo + (size_t)j0 * DD;

    const int lane = t & 63, wav = t >> 6;
    const int wr = wav >> 1, wc = wav & 1;   // 2x2 waves over 64x64 regions
    const int lr = lane & 15;                // fragment row (A) / col (B)
    const int lk = lane >> 4;                // k-group 0..3

    f32x4 acc[4][4];
    #pragma unroll
    for (int i = 0; i < 4; ++i)
        #pragma unroll
        for (int j = 0; j < 4; ++j) {
            acc[i][j][0] = 0.f; acc[i][j][1] = 0.f;
            acc[i][j][2] = 0.f; acc[i][j][3] = 0.f;
        }

    stage_tile(Ag, &As[0][0], t, 0);
    stage_tile(Bg, &Bs[0][0], t, 0);
    for (int c = 0; c < 16; ++c) {
        __syncthreads();                 // drains vmcnt: buf[c&1] ready
        if (c + 1 < 16) {                // prefetch overlaps this chunk's MFMA
            stage_tile(Ag, &As[(c + 1) & 1][0], t, (c + 1) * 32);
            stage_tile(Bg, &Bs[(c + 1) & 1][0], t, (c + 1) * 32);
        }
        const bf16_t* Ab = &As[c & 1][0];
        const bf16_t* Bb = &Bs[c & 1][0];
        bf16x8 bh[4];
        #pragma unroll
        for (int j = 0; j < 4; ++j)
            bh[j] = *(const bf16x8*)(Bb + (wc * 64 + j * 16 + lr) * 32 + lk * 8);
        #pragma unroll
        for (int i = 0; i < 4; ++i) {
            bf16x8 ah = *(const bf16x8*)(Ab + (wr * 64 + i * 16 + lr) * 32 + lk * 8);
            #pragma unroll
            for (int j = 0; j < 4; ++j)
                acc[i][j] = __builtin_amdgcn_mfma_f32_16x16x32_bf16(
                                ah, bh[j], acc[i][j], 0, 0, 0);
        }
    }

    // Epilogue (verified R4..R16): C/D col = lane&15, row = 4*(lane>>4)+reg.
    const bool farTile = (i0 - j0) >= 256;
    const float lb0 = lb[0];
    #pragma unroll
    for (int i = 0; i < 4; ++i) {
        #pragma unroll
        for (int j = 0; j < 4; ++j) {
            int gj    = j0 + wc * 64 + j * 16 + lr;
            int cbase = (jtl << 7) + wc * 64 + j * 16 + lr;
            #pragma unroll
            for (int rg = 0; rg < 4; ++rg) {
                int gi = i0 + wr * 64 + i * 16 + lk * 4 + rg;
                float v = acc[i][j][rg] * SCALE;
                if (farTile) v += lb0;
                else {
                    int rel = gj - gi;
                    int bi  = rel < -64 ? 0 : rel + 64;
                    v += lb[min(bi, 127)];
                    if (rel > 0) v = -INFINITY;
                }
                Sc[((size_t)b * SS + gi) * HALF + cbase] = v;
            }
        }
    }
}

// ---------------------------------------------------------------------------
// APPROX scores, FALLBACK path (byte-identical to R5/R8/R11 PASSING version).
// ---------------------------------------------------------------------------
__global__ __launch_bounds__(256, 2)
void scores_approx(const float* __restrict__ If, const float* __restrict__ Ff,
                   const float* __restrict__ lb, float* __restrict__ Sc, int h)
{
    __shared__ __align__(16) bf16_t AS[128][40];
    __shared__ __align__(16) bf16_t BS[128][40];
    const int t = threadIdx.x;

    int rt, jtl, jtg;
    decode_tile(blockIdx.x, h, rt, jtl, jtg);
    const int b  = blockIdx.z;
    const int i0 = rt << 7, j0 = jtg << 7;
    const size_t bo = (size_t)b * SS * DD;
    const float* Ag = If + bo + (size_t)i0 * DD;
    const float* Bg = Ff + bo + (size_t)j0 * DD;

    const int r0 = t >> 2;          // staged row 0..63 (+u=1 -> +64)
    const int cb = (t & 3) * 8;     // k-offset within 32-elem chunk

    const int lane = t & 63, wav = t >> 6;
    const int wr = wav >> 1, wc = wav & 1;
    const int lr = lane & 15;
    const int lk = lane >> 4;

    f32x4 acc[4][4];
    #pragma unroll
    for (int i = 0; i < 4; ++i)
        #pragma unroll
        for (int j = 0; j < 4; ++j) {
            acc[i][j][0] = 0.f; acc[i][j][1] = 0.f;
            acc[i][j][2] = 0.f; acc[i][j][3] = 0.f;
        }

    float4 aF[4], bF[4];
    #pragma unroll
    for (int u = 0; u < 2; ++u) {
        const float* ap = Ag + (size_t)(u * 64 + r0) * DD + cb;
        const float* bp = Bg + (size_t)(u * 64 + r0) * DD + cb;
        aF[2*u] = *(const float4*)ap;  aF[2*u+1] = *(const float4*)(ap + 4);
        bF[2*u] = *(const float4*)bp;  bF[2*u+1] = *(const float4*)(bp + 4);
    }

    for (int c = 0; c < 16; ++c) {
        __syncthreads();
        #pragma unroll
        for (int u = 0; u < 2; ++u) {
            float va[8] = {aF[2*u].x, aF[2*u].y, aF[2*u].z, aF[2*u].w,
                           aF[2*u+1].x, aF[2*u+1].y, aF[2*u+1].z, aF[2*u+1].w};
            float vb[8] = {bF[2*u].x, bF[2*u].y, bF[2*u].z, bF[2*u].w,
                           bF[2*u+1].x, bF[2*u+1].y, bF[2*u+1].z, bF[2*u+1].w};
            bf16x8 av8, bv8;
            #pragma unroll
            for (int e = 0; e < 8; ++e) {
                av8[e] = (bf16_t)va[e];
                bv8[e] = (bf16_t)vb[e];
            }
            int rw = u * 64 + r0;
            *(bf16x8*)&AS[rw][cb] = av8;
            *(bf16x8*)&BS[rw][cb] = bv8;
        }
        __syncthreads();
        if (c + 1 < 16) {
            int k0 = (c + 1) * 32;
            #pragma unroll
            for (int u = 0; u < 2; ++u) {
                const float* ap = Ag + (size_t)(u * 64 + r0) * DD + k0 + cb;
                const float* bp = Bg + (size_t)(u * 64 + r0) * DD + k0 + cb;
                aF[2*u] = *(const float4*)ap;  aF[2*u+1] = *(const float4*)(ap + 4);
                bF[2*u] = *(const float4*)bp;  bF[2*u+1] = *(const float4*)(bp + 4);
            }
        }
        bf16x8 bh[4];
        #pragma unroll
        for (int j = 0; j < 4; ++j)
            bh[j] = *(const bf16x8*)&BS[wc * 64 + j * 16 + lr][lk * 8];
        #pragma unroll
        for (int i = 0; i < 4; ++i) {
            bf16x8 ah = *(const bf16x8*)&AS[wr * 64 + i * 16 + lr][lk * 8];
            #pragma unroll
            for (int j = 0; j < 4; ++j)
                acc[i][j] = __builtin_amdgcn_mfma_f32_16x16x32_bf16(
                                ah, bh[j], acc[i][j], 0, 0, 0);
        }
    }

    const bool farTile = (i0 - j0) >= 256;
    const float lb0 = lb[0];
    #pragma unroll
    for (int i = 0; i < 4; ++i) {
        #pragma unroll
        for (int j = 0; j < 4; ++j) {
            int gj    = j0 + wc * 64 + j * 16 + lr;
            int cbase = (jtl << 7) + wc * 64 + j * 16 + lr;
            #pragma unroll
            for (int rg = 0; rg < 4; ++rg) {
                int gi = i0 + wr * 64 + i * 16 + lk * 4 + rg;
                float v = acc[i][j][rg] * SCALE;
                if (farTile) v += lb0;
                else {
                    int rel = gj - gi;
                    int bi  = rel < -64 ? 0 : rel + 64;
                    v += lb[min(bi, 127)];
                    if (rel > 0) v = -INFINITY;
                }
                Sc[((size_t)b * SS + gi) * HALF + cbase] = v;
            }
        }
    }
}

// ---------------------------------------------------------------------------
// Top-k with exact rescore. R17 change: LDS-OCCUPANCY fix. R16 counters:
// LDS_Block_Size=11776B caps residency at 13 WG/CU (< the 16-WG HW cap R8
// ran at); occupancy 27.7%. Shrink to ~6.4 KB: (a) gather chunk 32->16
// floats (sF 8.5->4.25 KB; 32 chunks, 2-per-iter hand-unrolled with NAMED
// gvA[4]/gvB[4] -- rule-#20-safe); (b) phase-1/3/4 arrays aliased into the
// sF pool (disjoint live ranges, barrier-separated). BITWISE-NEUTRAL: the
// global ascending-k fmaf sequence over identical floats is unchanged.
// ---------------------------------------------------------------------------
__global__ __launch_bounds__(64)
void topk_rescore(const float* __restrict__ Sc,
                  const float* __restrict__ If, const float* __restrict__ Ff,
                  const float* __restrict__ lb,
                  const float* __restrict__ p0v_in, const int* __restrict__ p0j_in,
                  float* __restrict__ p0v_out, int* __restrict__ p0j_out,
                  float* __restrict__ out, int h)
{
    // 4352 B pool: gather buffer sF[64][17] in phase 2; aliased to
    // sCand (phase 1 / pre-phase-2) and mv/mj/sOv/sOj (phases 3/4).
    __shared__ __align__(16) float sPool[64 * 17];
    __shared__ __align__(16) float sIrow[DD];       // 2 KB (live all phases)
    float* sF    = sPool;
    float* mv    = sPool;                  // [64]  (phase 3/4)
    int*   mj    = (int*)(sPool + 64);     // [64]
    float* sOv   = sPool + 128;            // [32]
    int*   sOj   = (int*)(sPool + 160);    // [32]
    int*   sCand = (int*)(sPool + 192);    // [64]  (phase 1 / pre-phase-2)

    const int lane = threadIdx.x;
    const int wid  = blockIdx.x;
    int b, i;
    if (h == 0) { b = wid >> 12; i = wid & 4095; }
    else        { b = wid >> 11; i = HALF + (wid & 2047); }
    const int nv = (h == 0) ? min(i + 1, HALF) : (i + 1 - HALF);  // finite count
    const size_t rb = ((size_t)b * SS + i) * HALF;
    const size_t bo = (size_t)b * SS * DD;
    const int l4 = lane * 4;

    // stage Irow -> LDS (overlaps with phase-1 Sc loads; barrier below covers)
    {
        const float* Irow = If + bo + (size_t)i * DD;
        float4 t0 = *(const float4*)&Irow[lane * 8];
        float4 t1 = *(const float4*)&Irow[lane * 8 + 4];
        *(float4*)&sIrow[lane * 8]     = t0;
        *(float4*)&sIrow[lane * 8 + 4] = t1;
    }

    int n = KSEL;
    int selj;
    if (nv <= KSEL) {
        // direct path: candidates = first 64 indices of this half.
        selj = h * HALF + lane;
    } else {
        // ---- phase 1a: load scores as monotone-sortable uint keys ----
        unsigned key[32];
        #pragma unroll
        for (int s = 0; s < 8; ++s) {
            int jb = s * 256 + l4;
            float4 f = make_float4(-INFINITY, -INFINITY, -INFINITY, -INFINITY);
            if (jb < nv) f = *(const float4*)&Sc[rb + jb];
            float vv[4] = {f.x, f.y, f.z, f.w};
            #pragma unroll
            for (int q = 0; q < 4; ++q) {
                unsigned ub = __float_as_uint(vv[q]);
                unsigned k  = (ub & 0x80000000u) ? ~ub : (ub | 0x80000000u);
                key[4*s+q] = ((jb + q) < nv) ? k : 0u;   // pads sort below -inf
            }
        }
        // ---- phase 1b: radix-descend threshold (wave-uniform control) ----
        unsigned cur = 0u;
        int csel = HALF;
        for (int bit = 31; bit >= 0 && csel > KSEL; --bit) {
            unsigned test = cur | (1u << bit);
            int cl = 0;
            #pragma unroll
            for (int c = 0; c < 32; ++c) cl += (key[c] >= test) ? 1 : 0;
            #pragma unroll
            for (int m = 1; m < 64; m <<= 1) cl += __shfl_xor(cl, m, 64);
            if (cl >= TGT) { cur = test; csel = cl; }
        }
        // ---- phase 1c: ballot-prefix compaction (cap 64) ----
        int base = 0;
        #pragma unroll
        for (int c = 0; c < 32; ++c) {
            bool surv = key[c] >= cur;
            unsigned long long mm = __ballot(surv);
            if (surv) {
                int pos = base + (int)__popcll(mm & ((1ull << lane) - 1ull));
                if (pos < KSEL)
                    sCand[pos] = (c >> 2) * 256 + l4 + (c & 3) + h * HALF;
            }
            base += (int)__popcll(mm);
        }
        n = min(base, KSEL);                 // n in [48, 64]
        __syncthreads();                     // sCand visible
        selj = (lane < n) ? sCand[lane] : (h * HALF);
    }

    // unified candidate table (pads too -> all 64 slots valid row indices)
    sCand[lane] = selj;
    __syncthreads();
    int cj[4];
    const int cw = (lane >> 2);              // candidate sub-index 0..15
    #pragma unroll
    for (int u = 0; u < 4; ++u) cj[u] = sCand[u * 16 + cw];
    __syncthreads();                         // sCand reads done; sF may reuse

    // ---- phase 2: exact rescore, cooperative gather + LDS transpose,
    //      16-float chunks, 2-deep NAMED-buffer prefetch ----
    float accd = 0.f;
    const int s4 = (lane & 3) * 4;           // float4 slot in 16-float chunk
    float4 gvA[4], gvB[4];
    #pragma unroll
    for (int u = 0; u < 4; ++u)              // prologue: chunk 0 -> gvA
        gvA[u] = *(const float4*)&Ff[bo + (size_t)cj[u] * DD + s4];
    #pragma unroll
    for (int u = 0; u < 4; ++u)              // prologue: chunk 1 -> gvB
        gvB[u] = *(const float4*)&Ff[bo + (size_t)cj[u] * DD + 16 + s4];
    #pragma unroll
    for (int kp = 0; kp < 16; ++kp) {        // 2 chunks (16 floats each) per iter
        const int kcA = 2 * kp, kcB = 2 * kp + 1;
        // --- even chunk: retire gvA, refill gvA <- chunk kcA+2 ---
        #pragma unroll
        for (int u = 0; u < 4; ++u) {
            float* p = &sF[(u * 16 + cw) * 17 + s4];
            *(float2*)&p[0] = make_float2(gvA[u].x, gvA[u].y);
            *(float2*)&p[2] = make_float2(gvA[u].z, gvA[u].w);
        }
        __syncthreads();                     // sF ready
        if (kcA + 2 < 32) {
            int k0n = (kcA + 2) * 16;
            #pragma unroll
            for (int u = 0; u < 4; ++u)
                gvA[u] = *(const float4*)&Ff[bo + (size_t)cj[u] * DD + k0n + s4];
        }
        {
            int k0 = kcA * 16;
            #pragma unroll
            for (int e2 = 0; e2 < 8; ++e2) {   // ascending k, exact chain order
                float2 fi = *(const float2*)&sIrow[k0 + e2 * 2];
                float2 fj = *(const float2*)&sF[lane * 17 + e2 * 2];
                accd = fmaf(fi.x, fj.x, accd);
                accd = fmaf(fi.y, fj.y, accd);
            }
        }
        __syncthreads();                     // reads done before overwrite
        // --- odd chunk: retire gvB, refill gvB <- chunk kcB+2 ---
        #pragma unroll
        for (int u = 0; u < 4; ++u) {
            float* p = &sF[(u * 16 + cw) * 17 + s4];
            *(float2*)&p[0] = make_float2(gvB[u].x, gvB[u].y);
            *(float2*)&p[2] = make_float2(gvB[u].z, gvB[u].w);
        }
        __syncthreads();                     // sF ready
        if (kcB + 2 < 32) {
            int k0n = (kcB + 2) * 16;
            #pragma unroll
            for (int u = 0; u < 4; ++u)
                gvB[u] = *(const float4*)&Ff[bo + (size_t)cj[u] * DD + k0n + s4];
        }
        {
            int k0 = kcB * 16;
            #pragma unroll
            for (int e2 = 0; e2 < 8; ++e2) {   // ascending k, exact chain order
                float2 fi = *(const float2*)&sIrow[k0 + e2 * 2];
                float2 fj = *(const float2*)&sF[lane * 17 + e2 * 2];
                accd = fmaf(fi.x, fj.x, accd);
                accd = fmaf(fi.y, fj.y, accd);
            }
        }
        __syncthreads();                     // reads done before overwrite
    }
    float selv;
    {
        float v = accd * SCALE;
        int rel = selj - i;
        int bi  = rel < -64 ? 0 : rel + 64;
        v += lb[min(bi, 127)];
        if (rel > 0) v = -INFINITY;
        selv = v;
    }
    if (lane >= n) selv = -INFINITY;   // pad lanes (rank >= 48 > 32: inert)

    // ---- phase 3: exact top-32 of the candidates (verified R4..R16) ----
    // (mv/mj alias the sF pool; last sF read is behind the loop's final barrier)
    mv[lane] = selv; mj[lane] = selj;
    __syncthreads();
    int rk = 0;
    #pragma unroll
    for (int f = 0; f < 64; ++f) {
        float fv = mv[f]; int fj = mj[f];
        rk += (fv > selv || (fv == selv && fj < selj)) ? 1 : 0;
    }
    if (rk < KTOP) { sOv[rk] = selv; sOj[rk] = selj; }
    __syncthreads();
    if (lane < KTOP) { selv = sOv[lane]; selj = sOj[lane]; }

    // ---- phase 4: partial store / merge / softmax (verified R4..R16) ----
    if (h == 0 && i >= HALF) {
        if (lane < KTOP) {
            size_t pb = ((size_t)b * HALF + (i - HALF)) * KTOP + lane;
            p0v_out[pb] = selv; p0j_out[pb] = selj;
        }
        return;
    }

    if (h == 1) {
        float p0v = 0.f; int p0j = 0;
        __syncthreads();   // phase-3 reads of mv done before merge overwrites
        if (lane < KTOP) {
            size_t pb = ((size_t)b * HALF + (i - HALF)) * KTOP + lane;
            p0v = p0v_in[pb]; p0j = p0j_in[pb];
            mv[lane] = p0v;         mj[lane] = p0j;
            mv[KTOP + lane] = selv; mj[KTOP + lane] = selj;
        }
        __syncthreads();
        int r0 = 0, r1 = 0;
        if (lane < KTOP) {
            for (int f = 0; f < 64; ++f) {
                float fv = mv[f]; int fj = mj[f];
                r0 += (fv > p0v || (fv == p0v && fj < p0j)) ? 1 : 0;
                r1 += (fv > selv || (fv == selv && fj < selj)) ? 1 : 0;
            }
        }
        __syncthreads();
        if (lane < KTOP) {
            if (r0 < KTOP) { sOv[r0] = p0v;  sOj[r0] = p0j;  }
            if (r1 < KTOP) { sOv[r1] = selv; sOj[r1] = selj; }
        }
        __syncthreads();
        if (lane < KTOP) { selv = sOv[lane]; selj = sOj[lane]; }
    }

    float mx = __shfl(selv, 0, 64);
    float e  = (lane < KTOP) ? expf(selv - mx) : 0.f;
    float sum = e;
    #pragma unroll
    for (int m = 1; m < 64; m <<= 1) sum += __shfl_xor(sum, m, 64);
    float invs = 1.0f / sum;
    if (lane < KTOP) {
        size_t ob = ((size_t)b * SS + i) * KTOP + lane;
        out[ob] = (float)selj;
        out[(size_t)BB * SS * KTOP + ob] = e * invs;
    }
}

// ---------------------------------------------------------------------------
extern "C" void kernel_launch(void* const* d_in, const int* in_sizes, int n_in,
                              void* d_out, int out_size, void* d_ws, size_t ws_size,
                              hipStream_t stream)
{
    const float* x   = (const float*)d_in[0];
    const float* Wi1 = (const float*)d_in[1];
    const float* bi1 = (const float*)d_in[2];
    const float* Wi2 = (const float*)d_in[3];
    const float* bi2 = (const float*)d_in[4];
    const float* Wf1 = (const float*)d_in[5];
    const float* bf1 = (const float*)d_in[6];
    const float* Wf2 = (const float*)d_in[7];
    const float* bf2 = (const float*)d_in[8];
    const float* lb  = (const float*)d_in[9];
    // d_in[10..13] = adaptive-k MLP (unused for outputs); d_in[14] = mask (all ones)

    const size_t NF = (size_t)BB * SS * DD;          // 4,194,304 floats
    float* ws       = (float*)d_ws;                  // base ~109 MB (R3-verified)
    float* intents  = ws;                            // NF
    float* features = ws + NF;                       // NF
    float* part0v   = ws + 2 * NF;
    int*   part0j   = (int*)(part0v + (size_t)BB * HALF * KTOP);
    float* Sc       = ws + 2 * NF + NF / 2;          // BB*SS*HALF floats (67 MB)
    float* Hi       = Sc;                            // MLP scratch inside Sc area
    float* Hf       = Sc + NF / 2;                   // (used before Sc is written)

    // Optional bf16 copies for the gload_lds scores path (+16.8 MB)
    const size_t baseFloats = 2 * NF + NF / 2 + 4 * NF;        // 6.5 NF
    const bool   useG       = ws_size >= (baseFloats + NF) * sizeof(float);
    bf16_t* IFb = (bf16_t*)(ws + baseFloats);                  // 2NF bf16 elems

    // MLP1 pair (x@W1+b1, GELU): z=0 -> intents path, z=1 -> features path
    gemm128<true ><<<dim3(DH / 128, 64, 2), 256, 0, stream>>>(
        x, x, Wi1, Wf1, bi1, bf1, Hi, Hf, nullptr, nullptr, DH, DD);
    // MLP2 pair (H@W2+b2); fused bf16 shadow write when workspace permits
    gemm128<false><<<dim3(DD / 128, 64, 2), 256, 0, stream>>>(
        Hi, Hf, Wi2, Wf2, bi2, bf2, intents, features,
        useG ? IFb : nullptr, useG ? (IFb + NF) : nullptr, DD, DH);

    if (useG) {
        scores_approx_g<<<dim3(392, 1, BB), 256, 0, stream>>>(
            IFb, IFb + NF, lb, Sc, 0);
    } else {
        scores_approx<<<dim3(392, 1, BB), 256, 0, stream>>>(
            intents, features, lb, Sc, 0);
    }
    topk_rescore<<<BB * SS, 64, 0, stream>>>(Sc, intents, features, lb,
                                             part0v, part0j, part0v, part0j,
                                             (float*)d_out, 0);
    if (useG) {
        scores_approx_g<<<dim3(136, 1, BB), 256, 0, stream>>>(
            IFb, IFb + NF, lb, Sc, 1);
    } else {
        scores_approx<<<dim3(136, 1, BB), 256, 0, stream>>>(
            intents, features, lb, Sc, 1);
    }
    topk_rescore<<<BB * HALF, 64, 0, stream>>>(Sc, intents, features, lb,
                                               part0v, part0j, part0v, part0j,
                                               (float*)d_out, 1);
}

// Round 18
// 450.970 us; speedup vs baseline: 2.2689x; 2.2689x over previous
//
#include <hip/hip_runtime.h>
#include <math.h>

// Problem constants (B=2, S=4096, D=512, MAXC=32, BIAS_LEN=128, TEMP=1)
#define BB   2
#define SS   4096
#define DD   512
#define DH   256      // D/2
#define KTOP 32
#define KSEL 64       // candidate slots (one per lane)
#define TGT  48       // threshold target: count(key >= T) >= TGT (margin 16 ranks)
#define HALF 2048     // j processed in two halves to bound workspace
#define SCALE 0.044194173824159216f   // 1/sqrt(512)

typedef __bf16 bf16_t;
typedef bf16_t bf16x8 __attribute__((ext_vector_type(8)));
typedef float  f32x4  __attribute__((ext_vector_type(4)));

// decode row of triangular tile list: q in [0, r_max*(r_max+1)/2)
__device__ __forceinline__ int tri_row(int q) {
    int r = (int)((sqrtf(8.0f * q + 1.0f) - 1.0f) * 0.5f);
    while ((r + 1) * (r + 2) / 2 <= q) ++r;
    while (r * (r + 1) / 2 > q) --r;
    return r;
}

// tile-id decode shared by both scores kernels (verified R0..R16)
__device__ __forceinline__ void decode_tile(int id, int h, int& rt, int& jtl, int& jtg) {
    if (h == 0) {
        if (id < 256) { rt = 16 + (id >> 4); jtl = id & 15; }
        else { int q = id - 256; rt = tri_row(q); jtl = q - rt * (rt + 1) / 2; }
        jtg = jtl;
    } else {
        int r = tri_row(id); rt = 16 + r;
        jtl = id - r * (r + 1) / 2; jtg = jtl + 16;
    }
}

// ---------------------------------------------------------------------------
// MLP GEMM v10 (R14 VERBATIM -- measured win, 478->452): 128x128, BK=64.
// Per-(m,n) chain BITWISE fixed (ascending-k fmaf, acc+bias, exact GELU).
// Optional bf16 shadow (R11-verified fusion).
// ---------------------------------------------------------------------------
template<bool GELU>
__global__ __launch_bounds__(256)
void gemm128(const float* __restrict__ A0, const float* __restrict__ A1,
             const float* __restrict__ W0, const float* __restrict__ W1,
             const float* __restrict__ b0, const float* __restrict__ b1,
             float* __restrict__ C0, float* __restrict__ C1,
             bf16_t* __restrict__ Bs0, bf16_t* __restrict__ Bs1,
             int N, int K)
{
    __shared__ float As[64][132];   // [k][m]  (BK=64)
    __shared__ float Ws[64][132];   // [k][n]
    const int t = threadIdx.x;
    const int z = blockIdx.z;
    const float* A    = z ? A1 : A0;
    const float* W    = z ? W1 : W0;
    const float* bias = z ? b1 : b0;
    float*       C    = z ? C1 : C0;
    bf16_t*      Bsh  = z ? Bs1 : Bs0;
    const int n0 = blockIdx.x * 128;
    const int m0 = blockIdx.y * 128;

    const int kq = t & 7;          // A stager: k-quad pair (4*kq and 4*kq+32)
    const int rr = t >> 3;         // A stager: row 0..31 (+u*32)
    const int wkr = t >> 3;        // W stager: k-row 0..31 (+v*32)
    const int wnc = (t & 7) * 16;  // W stager: col group (16 cols = 4 float4)
    const float* Ab = A + (size_t)m0 * K;
    const float* Wb = W + (size_t)0 * N + n0;

    const int lane = t & 63, wav = t >> 6;
    const int wr = wav >> 1, wc = wav & 1;     // wave 2x2 over 64x64 regions
    const int li = lane >> 3, lj = lane & 7;   // 8x8 lane grid

    float acc[8][8] = {};
    float4 aR[4][2], wR[2][4];
    #pragma unroll
    for (int u = 0; u < 4; ++u) {              // prologue: chunk 0 -> regs
        int r = u * 32 + rr;
        aR[u][0] = *(const float4*)&Ab[(size_t)r * K + 4 * kq];
        aR[u][1] = *(const float4*)&Ab[(size_t)r * K + 4 * kq + 32];
    }
    #pragma unroll
    for (int v = 0; v < 2; ++v) {
        int krow = v * 32 + wkr;
        #pragma unroll
        for (int u = 0; u < 4; ++u)
            wR[v][u] = *(const float4*)&Wb[(size_t)krow * N + wnc + 4 * u];
    }

    const int nch = K >> 6;                    // BK=64 chunks
    for (int c = 0; c < nch; ++c) {
        __syncthreads();
        #pragma unroll
        for (int u = 0; u < 4; ++u) {          // A regs -> LDS (both k-quads)
            int r = u * 32 + rr;
            As[4*kq+0][r]  = aR[u][0].x; As[4*kq+1][r]  = aR[u][0].y;
            As[4*kq+2][r]  = aR[u][0].z; As[4*kq+3][r]  = aR[u][0].w;
            As[4*kq+32][r] = aR[u][1].x; As[4*kq+33][r] = aR[u][1].y;
            As[4*kq+34][r] = aR[u][1].z; As[4*kq+35][r] = aR[u][1].w;
        }
        #pragma unroll
        for (int v = 0; v < 2; ++v) {          // W regs -> LDS
            int krow = v * 32 + wkr;
            #pragma unroll
            for (int u = 0; u < 4; ++u)
                *(float4*)&Ws[krow][wnc + 4 * u] = wR[v][u];
        }
        __syncthreads();
        if (c + 1 < nch) {                     // prefetch next chunk
            int k0 = (c + 1) * 64;
            #pragma unroll
            for (int u = 0; u < 4; ++u) {
                int r = u * 32 + rr;
                aR[u][0] = *(const float4*)&Ab[(size_t)r * K + k0 + 4 * kq];
                aR[u][1] = *(const float4*)&Ab[(size_t)r * K + k0 + 4 * kq + 32];
            }
            #pragma unroll
            for (int v = 0; v < 2; ++v) {
                int krow = k0 + v * 32 + wkr;
                #pragma unroll
                for (int u = 0; u < 4; ++u)
                    wR[v][u] = *(const float4*)&Wb[(size_t)krow * N + wnc + 4 * u];
            }
        }
        #pragma unroll
        for (int kk = 0; kk < 64; ++kk) {      // conflict-free: 8 addrs x 8-bcast
            float4 a0 = *(const float4*)&As[kk][wr * 64 + li * 8];
            float4 a1 = *(const float4*)&As[kk][wr * 64 + li * 8 + 4];
            float4 b0v = *(const float4*)&Ws[kk][wc * 64 + lj * 8];
            float4 b1v = *(const float4*)&Ws[kk][wc * 64 + lj * 8 + 4];
            float av[8] = {a0.x,a0.y,a0.z,a0.w,a1.x,a1.y,a1.z,a1.w};
            float bv[8] = {b0v.x,b0v.y,b0v.z,b0v.w,b1v.x,b1v.y,b1v.z,b1v.w};
            #pragma unroll
            for (int ri = 0; ri < 8; ++ri)
                #pragma unroll
                for (int rj = 0; rj < 8; ++rj)
                    acc[ri][rj] = fmaf(av[ri], bv[rj], acc[ri][rj]);
        }
    }

    const int nb = n0 + wc * 64 + lj * 8;
    float bv0[8];
    *(float4*)&bv0[0] = *(const float4*)&bias[nb];
    *(float4*)&bv0[4] = *(const float4*)&bias[nb + 4];
    #pragma unroll
    for (int ri = 0; ri < 8; ++ri) {
        int m = m0 + wr * 64 + li * 8 + ri;
        float o[8];
        #pragma unroll
        for (int rj = 0; rj < 8; ++rj) {
            float v = acc[ri][rj] + bv0[rj];   // same op order as R3: acc + bias
            if (GELU) v = 0.5f * v * (1.0f + erff(v * 0.7071067811865475f));
            o[rj] = v;
        }
        *(float4*)&C[(size_t)m * N + nb]     = make_float4(o[0],o[1],o[2],o[3]);
        *(float4*)&C[(size_t)m * N + nb + 4] = make_float4(o[4],o[5],o[6],o[7]);
        if (Bsh) {                              // fused bf16 shadow (R11)
            bf16x8 hv;
            #pragma unroll
            for (int rj = 0; rj < 8; ++rj) hv[rj] = (bf16_t)o[rj];
            *(bf16x8*)&Bsh[(size_t)m * N + nb] = hv;
        }
    }
}

// ---------------------------------------------------------------------------
// APPROX scores (verified R7..R16): bf16 inputs + global_load_lds(16B),
// m97 schedule (double-buffered [128][32] linear LDS, 1 barrier/chunk).
// fp32 Sc (bf16 Sc unsafe: radix tie-group truncation, R10).
// ---------------------------------------------------------------------------
__device__ __forceinline__ void stage_tile(const bf16_t* __restrict__ g,
                                           bf16_t* lds, int t, int k0)
{
    const int r0 = t >> 2;          // global row 0..63 (+64 for inst 1)
    const int cb = (t & 3) * 8;     // element offset within 32-elem slice
    const int wb = (t >> 6) * 512;  // wave-uniform LDS element base
    #pragma unroll
    for (int inst = 0; inst < 2; ++inst) {
        const bf16_t* gp = g + (size_t)(inst * 64 + r0) * DD + (k0 + cb);
        bf16_t* lp = lds + inst * 2048 + wb;   // + lane*8 elems added by HW
        __builtin_amdgcn_global_load_lds(
            (const __attribute__((address_space(1))) void*)gp,
            (__attribute__((address_space(3))) void*)lp, 16, 0, 0);
    }
}

__global__ __launch_bounds__(256, 2)
void scores_approx_g(const bf16_t* __restrict__ Ib, const bf16_t* __restrict__ Fb,
                     const float* __restrict__ lb, float* __restrict__ Sc, int h)
{
    __shared__ bf16_t As[2][128 * 32];
    __shared__ bf16_t Bs[2][128 * 32];
    const int t = threadIdx.x;

    int rt, jtl, jtg;
    decode_tile(blockIdx.x, h, rt, jtl, jtg);
    const int b  = blockIdx.z;
    const int i0 = rt << 7, j0 = jtg << 7;
    const size_t bo = (size_t)b * SS * DD;
    const bf16_t* Ag = Ib + bo + (size_t)i0 * DD;
    const bf16_t* Bg = Fb + bo + (size_t)j0 * DD;

    const int lane = t & 63, wav = t >> 6;
    const int wr = wav >> 1, wc = wav & 1;   // 2x2 waves over 64x64 regions
    const int lr = lane & 15;                // fragment row (A) / col (B)
    const int lk = lane >> 4;                // k-group 0..3

    f32x4 acc[4][4];
    #pragma unroll
    for (int i = 0; i < 4; ++i)
        #pragma unroll
        for (int j = 0; j < 4; ++j) {
            acc[i][j][0] = 0.f; acc[i][j][1] = 0.f;
            acc[i][j][2] = 0.f; acc[i][j][3] = 0.f;
        }

    stage_tile(Ag, &As[0][0], t, 0);
    stage_tile(Bg, &Bs[0][0], t, 0);
    for (int c = 0; c < 16; ++c) {
        __syncthreads();                 // drains vmcnt: buf[c&1] ready
        if (c + 1 < 16) {                // prefetch overlaps this chunk's MFMA
            stage_tile(Ag, &As[(c + 1) & 1][0], t, (c + 1) * 32);
            stage_tile(Bg, &Bs[(c + 1) & 1][0], t, (c + 1) * 32);
        }
        const bf16_t* Ab = &As[c & 1][0];
        const bf16_t* Bb = &Bs[c & 1][0];
        bf16x8 bh[4];
        #pragma unroll
        for (int j = 0; j < 4; ++j)
            bh[j] = *(const bf16x8*)(Bb + (wc * 64 + j * 16 + lr) * 32 + lk * 8);
        #pragma unroll
        for (int i = 0; i < 4; ++i) {
            bf16x8 ah = *(const bf16x8*)(Ab + (wr * 64 + i * 16 + lr) * 32 + lk * 8);
            #pragma unroll
            for (int j = 0; j < 4; ++j)
                acc[i][j] = __builtin_amdgcn_mfma_f32_16x16x32_bf16(
                                ah, bh[j], acc[i][j], 0, 0, 0);
        }
    }

    // Epilogue (verified R4..R16): C/D col = lane&15, row = 4*(lane>>4)+reg.
    const bool farTile = (i0 - j0) >= 256;
    const float lb0 = lb[0];
    #pragma unroll
    for (int i = 0; i < 4; ++i) {
        #pragma unroll
        for (int j = 0; j < 4; ++j) {
            int gj    = j0 + wc * 64 + j * 16 + lr;
            int cbase = (jtl << 7) + wc * 64 + j * 16 + lr;
            #pragma unroll
            for (int rg = 0; rg < 4; ++rg) {
                int gi = i0 + wr * 64 + i * 16 + lk * 4 + rg;
                float v = acc[i][j][rg] * SCALE;
                if (farTile) v += lb0;
                else {
                    int rel = gj - gi;
                    int bi  = rel < -64 ? 0 : rel + 64;
                    v += lb[min(bi, 127)];
                    if (rel > 0) v = -INFINITY;
                }
                Sc[((size_t)b * SS + gi) * HALF + cbase] = v;
            }
        }
    }
}

// ---------------------------------------------------------------------------
// APPROX scores, FALLBACK path (byte-identical to R5/R8/R11 PASSING version).
// ---------------------------------------------------------------------------
__global__ __launch_bounds__(256, 2)
void scores_approx(const float* __restrict__ If, const float* __restrict__ Ff,
                   const float* __restrict__ lb, float* __restrict__ Sc, int h)
{
    __shared__ __align__(16) bf16_t AS[128][40];
    __shared__ __align__(16) bf16_t BS[128][40];
    const int t = threadIdx.x;

    int rt, jtl, jtg;
    decode_tile(blockIdx.x, h, rt, jtl, jtg);
    const int b  = blockIdx.z;
    const int i0 = rt << 7, j0 = jtg << 7;
    const size_t bo = (size_t)b * SS * DD;
    const float* Ag = If + bo + (size_t)i0 * DD;
    const float* Bg = Ff + bo + (size_t)j0 * DD;

    const int r0 = t >> 2;          // staged row 0..63 (+u=1 -> +64)
    const int cb = (t & 3) * 8;     // k-offset within 32-elem chunk

    const int lane = t & 63, wav = t >> 6;
    const int wr = wav >> 1, wc = wav & 1;
    const int lr = lane & 15;
    const int lk = lane >> 4;

    f32x4 acc[4][4];
    #pragma unroll
    for (int i = 0; i < 4; ++i)
        #pragma unroll
        for (int j = 0; j < 4; ++j) {
            acc[i][j][0] = 0.f; acc[i][j][1] = 0.f;
            acc[i][j][2] = 0.f; acc[i][j][3] = 0.f;
        }

    float4 aF[4], bF[4];
    #pragma unroll
    for (int u = 0; u < 2; ++u) {
        const float* ap = Ag + (size_t)(u * 64 + r0) * DD + cb;
        const float* bp = Bg + (size_t)(u * 64 + r0) * DD + cb;
        aF[2*u] = *(const float4*)ap;  aF[2*u+1] = *(const float4*)(ap + 4);
        bF[2*u] = *(const float4*)bp;  bF[2*u+1] = *(const float4*)(bp + 4);
    }

    for (int c = 0; c < 16; ++c) {
        __syncthreads();
        #pragma unroll
        for (int u = 0; u < 2; ++u) {
            float va[8] = {aF[2*u].x, aF[2*u].y, aF[2*u].z, aF[2*u].w,
                           aF[2*u+1].x, aF[2*u+1].y, aF[2*u+1].z, aF[2*u+1].w};
            float vb[8] = {bF[2*u].x, bF[2*u].y, bF[2*u].z, bF[2*u].w,
                           bF[2*u+1].x, bF[2*u+1].y, bF[2*u+1].z, bF[2*u+1].w};
            bf16x8 av8, bv8;
            #pragma unroll
            for (int e = 0; e < 8; ++e) {
                av8[e] = (bf16_t)va[e];
                bv8[e] = (bf16_t)vb[e];
            }
            int rw = u * 64 + r0;
            *(bf16x8*)&AS[rw][cb] = av8;
            *(bf16x8*)&BS[rw][cb] = bv8;
        }
        __syncthreads();
        if (c + 1 < 16) {
            int k0 = (c + 1) * 32;
            #pragma unroll
            for (int u = 0; u < 2; ++u) {
                const float* ap = Ag + (size_t)(u * 64 + r0) * DD + k0 + cb;
                const float* bp = Bg + (size_t)(u * 64 + r0) * DD + k0 + cb;
                aF[2*u] = *(const float4*)ap;  aF[2*u+1] = *(const float4*)(ap + 4);
                bF[2*u] = *(const float4*)bp;  bF[2*u+1] = *(const float4*)(bp + 4);
            }
        }
        bf16x8 bh[4];
        #pragma unroll
        for (int j = 0; j < 4; ++j)
            bh[j] = *(const bf16x8*)&BS[wc * 64 + j * 16 + lr][lk * 8];
        #pragma unroll
        for (int i = 0; i < 4; ++i) {
            bf16x8 ah = *(const bf16x8*)&AS[wr * 64 + i * 16 + lr][lk * 8];
            #pragma unroll
            for (int j = 0; j < 4; ++j)
                acc[i][j] = __builtin_amdgcn_mfma_f32_16x16x32_bf16(
                                ah, bh[j], acc[i][j], 0, 0, 0);
        }
    }

    const bool farTile = (i0 - j0) >= 256;
    const float lb0 = lb[0];
    #pragma unroll
    for (int i = 0; i < 4; ++i) {
        #pragma unroll
        for (int j = 0; j < 4; ++j) {
            int gj    = j0 + wc * 64 + j * 16 + lr;
            int cbase = (jtl << 7) + wc * 64 + j * 16 + lr;
            #pragma unroll
            for (int rg = 0; rg < 4; ++rg) {
                int gi = i0 + wr * 64 + i * 16 + lk * 4 + rg;
                float v = acc[i][j][rg] * SCALE;
                if (farTile) v += lb0;
                else {
                    int rel = gj - gi;
                    int bi  = rel < -64 ? 0 : rel + 64;
                    v += lb[min(bi, 127)];
                    if (rel > 0) v = -INFINITY;
                }
                Sc[((size_t)b * SS + gi) * HALF + cbase] = v;
            }
        }
    }
}

// ---------------------------------------------------------------------------
// Top-k with exact rescore (R16 VERBATIM -- measured best, 451.9us total).
// R17's LDS-occupancy shrink REVERTED: occupancy rose 27.7->49.8% while the
// kernel got 5x SLOWER (doubled barrier count = doubled vmcnt(0) drains) --
// occupancy definitively not the limiter. Cooperative gather + LDS
// transpose (R13) + 2-deep NAMED-buffer prefetch (rule-#20-safe, R16).
// Phases 1/3/4 = R8/R11 verified; phase-2 chain bitwise round-0.
// ---------------------------------------------------------------------------
__global__ __launch_bounds__(64)
void topk_rescore(const float* __restrict__ Sc,
                  const float* __restrict__ If, const float* __restrict__ Ff,
                  const float* __restrict__ lb,
                  const float* __restrict__ p0v_in, const int* __restrict__ p0j_in,
                  float* __restrict__ p0v_out, int* __restrict__ p0j_out,
                  float* __restrict__ out, int h)
{
    __shared__ float mv[64];
    __shared__ int   mj[64];
    __shared__ float sOv[32];
    __shared__ int   sOj[32];
    __shared__ int   sCand[64];
    __shared__ __align__(16) float sIrow[DD];       // 2 KB
    __shared__ __align__(16) float sF[64 * 34];     // 8.5 KB, stride 34

    const int lane = threadIdx.x;
    const int wid  = blockIdx.x;
    int b, i;
    if (h == 0) { b = wid >> 12; i = wid & 4095; }
    else        { b = wid >> 11; i = HALF + (wid & 2047); }
    const int nv = (h == 0) ? min(i + 1, HALF) : (i + 1 - HALF);  // finite count
    const size_t rb = ((size_t)b * SS + i) * HALF;
    const size_t bo = (size_t)b * SS * DD;
    const int l4 = lane * 4;

    // stage Irow -> LDS (overlaps with phase-1 Sc loads; barrier below covers)
    {
        const float* Irow = If + bo + (size_t)i * DD;
        float4 t0 = *(const float4*)&Irow[lane * 8];
        float4 t1 = *(const float4*)&Irow[lane * 8 + 4];
        *(float4*)&sIrow[lane * 8]     = t0;
        *(float4*)&sIrow[lane * 8 + 4] = t1;
    }

    int n = KSEL;
    int selj;
    if (nv <= KSEL) {
        // direct path: candidates = first 64 indices of this half.
        selj = h * HALF + lane;
    } else {
        // ---- phase 1a: load scores as monotone-sortable uint keys ----
        unsigned key[32];
        #pragma unroll
        for (int s = 0; s < 8; ++s) {
            int jb = s * 256 + l4;
            float4 f = make_float4(-INFINITY, -INFINITY, -INFINITY, -INFINITY);
            if (jb < nv) f = *(const float4*)&Sc[rb + jb];
            float vv[4] = {f.x, f.y, f.z, f.w};
            #pragma unroll
            for (int q = 0; q < 4; ++q) {
                unsigned ub = __float_as_uint(vv[q]);
                unsigned k  = (ub & 0x80000000u) ? ~ub : (ub | 0x80000000u);
                key[4*s+q] = ((jb + q) < nv) ? k : 0u;   // pads sort below -inf
            }
        }
        // ---- phase 1b: radix-descend threshold (wave-uniform control) ----
        unsigned cur = 0u;
        int csel = HALF;
        for (int bit = 31; bit >= 0 && csel > KSEL; --bit) {
            unsigned test = cur | (1u << bit);
            int cl = 0;
            #pragma unroll
            for (int c = 0; c < 32; ++c) cl += (key[c] >= test) ? 1 : 0;
            #pragma unroll
            for (int m = 1; m < 64; m <<= 1) cl += __shfl_xor(cl, m, 64);
            if (cl >= TGT) { cur = test; csel = cl; }
        }
        // ---- phase 1c: ballot-prefix compaction (cap 64) ----
        int base = 0;
        #pragma unroll
        for (int c = 0; c < 32; ++c) {
            bool surv = key[c] >= cur;
            unsigned long long mm = __ballot(surv);
            if (surv) {
                int pos = base + (int)__popcll(mm & ((1ull << lane) - 1ull));
                if (pos < KSEL)
                    sCand[pos] = (c >> 2) * 256 + l4 + (c & 3) + h * HALF;
            }
            base += (int)__popcll(mm);
        }
        n = min(base, KSEL);                 // n in [48, 64]
        __syncthreads();                     // sCand visible
        selj = (lane < n) ? sCand[lane] : (h * HALF);
    }

    // unified candidate table (pads too -> all 64 slots valid row indices)
    sCand[lane] = selj;
    __syncthreads();
    int cj[8];
    #pragma unroll
    for (int u = 0; u < 8; ++u) cj[u] = sCand[u * 8 + (lane >> 3)];

    // ---- phase 2: exact rescore, cooperative gather + LDS transpose,
    //      2-deep prefetch with NAMED buffers (rule-#20-safe) ----
    float accd = 0.f;
    const int s4 = (lane & 7) * 4;           // float4 slot in 32-float chunk
    const int cw = (lane >> 3);              // candidate sub-index for loads
    float4 gvA[8], gvB[8];
    #pragma unroll
    for (int u = 0; u < 8; ++u)              // prologue: chunk 0 -> gvA
        gvA[u] = *(const float4*)&Ff[bo + (size_t)cj[u] * DD + s4];
    #pragma unroll
    for (int u = 0; u < 8; ++u)              // prologue: chunk 1 -> gvB
        gvB[u] = *(const float4*)&Ff[bo + (size_t)cj[u] * DD + 32 + s4];
    #pragma unroll
    for (int kp = 0; kp < 8; ++kp) {         // 2 chunks per iteration
        const int kcA = 2 * kp, kcB = 2 * kp + 1;
        // --- even chunk: retire gvA, refill gvA <- chunk kcA+2 ---
        #pragma unroll
        for (int u = 0; u < 8; ++u) {
            float* p = &sF[(u * 8 + cw) * 34 + s4];
            *(float2*)&p[0] = make_float2(gvA[u].x, gvA[u].y);
            *(float2*)&p[2] = make_float2(gvA[u].z, gvA[u].w);
        }
        __syncthreads();                     // sF ready
        if (kcA + 2 < 16) {
            int k0n = (kcA + 2) * 32;
            #pragma unroll
            for (int u = 0; u < 8; ++u)
                gvA[u] = *(const float4*)&Ff[bo + (size_t)cj[u] * DD + k0n + s4];
        }
        {
            int k0 = kcA * 32;
            #pragma unroll
            for (int e2 = 0; e2 < 16; ++e2) {  // ascending k, exact chain order
                float2 fi = *(const float2*)&sIrow[k0 + e2 * 2];
                float2 fj = *(const float2*)&sF[lane * 34 + e2 * 2];
                accd = fmaf(fi.x, fj.x, accd);
                accd = fmaf(fi.y, fj.y, accd);
            }
        }
        __syncthreads();                     // reads done before overwrite
        // --- odd chunk: retire gvB, refill gvB <- chunk kcB+2 ---
        #pragma unroll
        for (int u = 0; u < 8; ++u) {
            float* p = &sF[(u * 8 + cw) * 34 + s4];
            *(float2*)&p[0] = make_float2(gvB[u].x, gvB[u].y);
            *(float2*)&p[2] = make_float2(gvB[u].z, gvB[u].w);
        }
        __syncthreads();                     // sF ready
        if (kcB + 2 < 16) {
            int k0n = (kcB + 2) * 32;
            #pragma unroll
            for (int u = 0; u < 8; ++u)
                gvB[u] = *(const float4*)&Ff[bo + (size_t)cj[u] * DD + k0n + s4];
        }
        {
            int k0 = kcB * 32;
            #pragma unroll
            for (int e2 = 0; e2 < 16; ++e2) {  // ascending k, exact chain order
                float2 fi = *(const float2*)&sIrow[k0 + e2 * 2];
                float2 fj = *(const float2*)&sF[lane * 34 + e2 * 2];
                accd = fmaf(fi.x, fj.x, accd);
                accd = fmaf(fi.y, fj.y, accd);
            }
        }
        __syncthreads();                     // reads done before overwrite
    }
    float selv;
    {
        float v = accd * SCALE;
        int rel = selj - i;
        int bi  = rel < -64 ? 0 : rel + 64;
        v += lb[min(bi, 127)];
        if (rel > 0) v = -INFINITY;
        selv = v;
    }
    if (lane >= n) selv = -INFINITY;   // pad lanes (rank >= 48 > 32: inert)

    // ---- phase 3: exact top-32 of the candidates (verified R4..R16) ----
    mv[lane] = selv; mj[lane] = selj;
    __syncthreads();
    int rk = 0;
    #pragma unroll
    for (int f = 0; f < 64; ++f) {
        float fv = mv[f]; int fj = mj[f];
        rk += (fv > selv || (fv == selv && fj < selj)) ? 1 : 0;
    }
    if (rk < KTOP) { sOv[rk] = selv; sOj[rk] = selj; }
    __syncthreads();
    if (lane < KTOP) { selv = sOv[lane]; selj = sOj[lane]; }

    // ---- phase 4: partial store / merge / softmax (verified R4..R16) ----
    if (h == 0 && i >= HALF) {
        if (lane < KTOP) {
            size_t pb = ((size_t)b * HALF + (i - HALF)) * KTOP + lane;
            p0v_out[pb] = selv; p0j_out[pb] = selj;
        }
        return;
    }

    if (h == 1) {
        float p0v = 0.f; int p0j = 0;
        __syncthreads();   // phase-3 reads of mv done before merge overwrites
        if (lane < KTOP) {
            size_t pb = ((size_t)b * HALF + (i - HALF)) * KTOP + lane;
            p0v = p0v_in[pb]; p0j = p0j_in[pb];
            mv[lane] = p0v;         mj[lane] = p0j;
            mv[KTOP + lane] = selv; mj[KTOP + lane] = selj;
        }
        __syncthreads();
        int r0 = 0, r1 = 0;
        if (lane < KTOP) {
            for (int f = 0; f < 64; ++f) {
                float fv = mv[f]; int fj = mj[f];
                r0 += (fv > p0v || (fv == p0v && fj < p0j)) ? 1 : 0;
                r1 += (fv > selv || (fv == selv && fj < selj)) ? 1 : 0;
            }
        }
        __syncthreads();
        if (lane < KTOP) {
            if (r0 < KTOP) { sOv[r0] = p0v;  sOj[r0] = p0j;  }
            if (r1 < KTOP) { sOv[r1] = selv; sOj[r1] = selj; }
        }
        __syncthreads();
        if (lane < KTOP) { selv = sOv[lane]; selj = sOj[lane]; }
    }

    float mx = __shfl(selv, 0, 64);
    float e  = (lane < KTOP) ? expf(selv - mx) : 0.f;
    float sum = e;
    #pragma unroll
    for (int m = 1; m < 64; m <<= 1) sum += __shfl_xor(sum, m, 64);
    float invs = 1.0f / sum;
    if (lane < KTOP) {
        size_t ob = ((size_t)b * SS + i) * KTOP + lane;
        out[ob] = (float)selj;
        out[(size_t)BB * SS * KTOP + ob] = e * invs;
    }
}

// ---------------------------------------------------------------------------
extern "C" void kernel_launch(void* const* d_in, const int* in_sizes, int n_in,
                              void* d_out, int out_size, void* d_ws, size_t ws_size,
                              hipStream_t stream)
{
    const float* x   = (const float*)d_in[0];
    const float* Wi1 = (const float*)d_in[1];
    const float* bi1 = (const float*)d_in[2];
    const float* Wi2 = (const float*)d_in[3];
    const float* bi2 = (const float*)d_in[4];
    const float* Wf1 = (const float*)d_in[5];
    const float* bf1 = (const float*)d_in[6];
    const float* Wf2 = (const float*)d_in[7];
    const float* bf2 = (const float*)d_in[8];
    const float* lb  = (const float*)d_in[9];
    // d_in[10..13] = adaptive-k MLP (unused for outputs); d_in[14] = mask (all ones)

    const size_t NF = (size_t)BB * SS * DD;          // 4,194,304 floats
    float* ws       = (float*)d_ws;                  // base ~109 MB (R3-verified)
    float* intents  = ws;                            // NF
    float* features = ws + NF;                       // NF
    float* part0v   = ws + 2 * NF;
    int*   part0j   = (int*)(part0v + (size_t)BB * HALF * KTOP);
    float* Sc       = ws + 2 * NF + NF / 2;          // BB*SS*HALF floats (67 MB)
    float* Hi       = Sc;                            // MLP scratch inside Sc area
    float* Hf       = Sc + NF / 2;                   // (used before Sc is written)

    // Optional bf16 copies for the gload_lds scores path (+16.8 MB)
    const size_t baseFloats = 2 * NF + NF / 2 + 4 * NF;        // 6.5 NF
    const bool   useG       = ws_size >= (baseFloats + NF) * sizeof(float);
    bf16_t* IFb = (bf16_t*)(ws + baseFloats);                  // 2NF bf16 elems

    // MLP1 pair (x@W1+b1, GELU): z=0 -> intents path, z=1 -> features path
    gemm128<true ><<<dim3(DH / 128, 64, 2), 256, 0, stream>>>(
        x, x, Wi1, Wf1, bi1, bf1, Hi, Hf, nullptr, nullptr, DH, DD);
    // MLP2 pair (H@W2+b2); fused bf16 shadow write when workspace permits
    gemm128<false><<<dim3(DD / 128, 64, 2), 256, 0, stream>>>(
        Hi, Hf, Wi2, Wf2, bi2, bf2, intents, features,
        useG ? IFb : nullptr, useG ? (IFb + NF) : nullptr, DD, DH);

    if (useG) {
        scores_approx_g<<<dim3(392, 1, BB), 256, 0, stream>>>(
            IFb, IFb + NF, lb, Sc, 0);
    } else {
        scores_approx<<<dim3(392, 1, BB), 256, 0, stream>>>(
            intents, features, lb, Sc, 0);
    }
    topk_rescore<<<BB * SS, 64, 0, stream>>>(Sc, intents, features, lb,
                                             part0v, part0j, part0v, part0j,
                                             (float*)d_out, 0);
    if (useG) {
        scores_approx_g<<<dim3(136, 1, BB), 256, 0, stream>>>(
            IFb, IFb + NF, lb, Sc, 1);
    } else {
        scores_approx<<<dim3(136, 1, BB), 256, 0, stream>>>(
            intents, features, lb, Sc, 1);
    }
    topk_rescore<<<BB * HALF, 64, 0, stream>>>(Sc, intents, features, lb,
                                               part0v, part0j, part0v, part0j,
                                               (float*)d_out, 1);
}